// Round 1
// 301.006 us; speedup vs baseline: 1.0237x; 1.0237x over previous
//
#include <hip/hip_runtime.h>
#include <hip/hip_bf16.h>

// f32-storage implementation. BK=64 async GEMM with DOUBLE-BUFFERED LDS
// (issue-early prefetch, T3 2-phase pattern), XOR-swizzled LDS, fast-tanh
// epilogues, d1 fused into the circuit kernel.
// ws layout (bytes):
//   [256)        gates: 384 f32
//   [4096)       biasf: 6272 f32
//   [294912)     encf  f32  [4096][256]                     ends 4,489,216
//   [4489216)    P     bf16 4096x1024 (h1,d2,d4)            ends 12,877,824
//   [12877824)   Q     bf16 4096x512  (h2,d1,d3)            ends 17,072,128
//   [17072128)   WT    bf16 transposed weights (13.18 MB)   ends 30,253,056
//   [30253056)   Xb    bf16 4096x2560 (x converted)         ends 51,224,576

using bf16 = __hip_bfloat16;
typedef __attribute__((ext_vector_type(8))) short short8;
typedef __attribute__((ext_vector_type(4))) short short4v;
typedef __attribute__((ext_vector_type(4))) float f32x4;

__device__ inline void stf(float* p, size_t i, float v) { p[i] = v; }
__device__ inline void stf(bf16* p, size_t i, float v) { p[i] = __float2bfloat16(v); }

// fast tanh: ~5 VALU ops, clamped so exp stays finite (no inf/inf NaN).
// |err| ~1e-6, far below the bf16-level output threshold.
__device__ inline float fast_tanh(float x) {
  x = fminf(fmaxf(x, -15.0f), 15.0f);
  float t = __expf(2.0f * x);
  return __fdividef(t - 1.0f, t + 1.0f);
}

__device__ inline short f2bs(float x) {
  bf16 h = __float2bfloat16(x);
  return *reinterpret_cast<short*>(&h);
}
__device__ inline short8 ld8b(const float* p) {
  const float4 a = ((const float4*)p)[0];
  const float4 b = ((const float4*)p)[1];
  short8 r;
  r[0] = f2bs(a.x); r[1] = f2bs(a.y); r[2] = f2bs(a.z); r[3] = f2bs(a.w);
  r[4] = f2bs(b.x); r[5] = f2bs(b.y); r[6] = f2bs(b.z); r[7] = f2bs(b.w);
  return r;
}
__device__ inline short4v ld4b(const float* p) {
  const float4 a = *(const float4*)p;
  short4v r;
  r[0] = f2bs(a.x); r[1] = f2bs(a.y); r[2] = f2bs(a.z); r[3] = f2bs(a.w);
  return r;
}

__device__ inline void async_load16(const bf16* g, short* l) {
  __builtin_amdgcn_global_load_lds(
      (const __attribute__((address_space(1))) unsigned int*)g,
      (__attribute__((address_space(3))) unsigned int*)l, 16, 0, 0);
}

// ---------------- prep: weights -> WT bf16 [N][Kp]; biases; gates; x -> bf16
__global__ __launch_bounds__(256) void prep_all(
    const float* w0, const float* w1, const float* w2, const float* w3,
    const float* w4, const float* w5, const float* w6, const float* w7,
    const float* b0, const float* b1, const float* b2, const float* b3,
    const float* b4, const float* b5, const float* b6, const float* b7,
    const float* dp, const float* xf,
    bf16* __restrict__ wt, float* __restrict__ biasf, float* __restrict__ gw,
    bf16* __restrict__ xb, int do_x) {
  const int bid = blockIdx.x;
  const int tid = threadIdx.x;
  const int Ks[8]  = {2560, 1024, 512, 24, 128, 256, 512, 1024};
  const int Ns[8]  = {1024, 512, 256, 128, 256, 512, 1024, 2560};
  const int cum[8] = {2560, 3072, 3200, 3204, 3236, 3364, 3876, 6436};
  const long wto[8] = {0, 2621440, 3145728, 3276800, 3280896, 3313664, 3444736, 3969024};
  const float* Wp[8] = {w0, w1, w2, w3, w4, w5, w6, w7};
  const float* Bp[8] = {b0, b1, b2, b3, b4, b5, b6, b7};
  const int boff[8] = {0, 1024, 1536, 1792, 1920, 2176, 2688, 3712};

  if (bid < 6436) {
    int t = 0;
    while (bid >= cum[t]) t++;
    int base = t ? cum[t - 1] : 0;
    int local = bid - base;
    int K = Ks[t], N = Ns[t];
    int tk = (K + 31) >> 5;
    int kt = local % tk, nt = local / tk;
    int Kp = tk << 5;
    __shared__ short tile[32][33];
    int r = tid >> 3, c4 = (tid & 7) << 2;
    int gk = kt * 32 + r, gn = nt * 32 + c4;
    short4v v;
    if (gk < K) v = ld4b(Wp[t] + (size_t)gk * N + gn);
    else { v[0] = 0; v[1] = 0; v[2] = 0; v[3] = 0; }
    tile[r][c4] = v[0]; tile[r][c4 + 1] = v[1]; tile[r][c4 + 2] = v[2]; tile[r][c4 + 3] = v[3];
    __syncthreads();
    int n = tid >> 3, k4 = (tid & 7) << 2;
    short4v o;
    o[0] = tile[k4][n]; o[1] = tile[k4 + 1][n]; o[2] = tile[k4 + 2][n]; o[3] = tile[k4 + 3][n];
    *(short4v*)&wt[wto[t] + (size_t)(nt * 32 + n) * Kp + kt * 32 + k4] = o;
  } else if (bid < 6444) {
    int b = bid - 6436;
    int nb = Ns[b];
    for (int t2 = tid; t2 < nb; t2 += 256)
      biasf[boff[b] + t2] = Bp[b][t2];
  } else if (bid == 6444) {
    int g = tid;
    if (g < 48) {
      float phi = dp[g * 3 + 0], theta = dp[g * 3 + 1], omega = dp[g * 3 + 2];
      float c = cosf(0.5f * theta), s = sinf(0.5f * theta);
      float a = 0.5f * (phi + omega), d = 0.5f * (phi - omega);
      float ca = cosf(a), sa = sinf(a), cd = cosf(d), sd = sinf(d);
      float* o = gw + g * 8;
      o[0] =  ca * c; o[1] = -sa * c;
      o[2] = -cd * s; o[3] = -sd * s;
      o[4] =  cd * s; o[5] = -sd * s;
      o[6] =  ca * c; o[7] =  sa * c;
    }
  } else if (do_x) {
    long i = ((long)(bid - 6445) * 256 + tid) * 8;
    if (i < 10485760L) {
      short8 v = ld8b(xf + i);
      *(short8*)((short*)xb + i) = v;
    }
  }
}

// ---------------- async MFMA GEMM: C = act(A @ Bt^T + bias)
// Double-buffered LDS, issue-early prefetch (T3 2-phase): stage tile t+1
// BEFORE the ds_read+MFMA of tile t, so the global_load_lds latency hides
// under the compute phase; the end-of-iteration __syncthreads (implicit
// vmcnt(0) drain) guarantees the prefetch landed before it is consumed.
// XOR-swizzled LDS chunk layout (conflicts -> 0).
template <int BM, int BN, int BK, int WR, int WC, int ACT, typename TC>
__global__ __launch_bounds__(256) void gemm_async(const bf16* __restrict__ A,
                                                  const bf16* __restrict__ Bt,
                                                  const float* __restrict__ bias,
                                                  TC* __restrict__ C,
                                                  int M, int N, int K) {
  constexpr int CPR = BK / 8;
  constexpr int MASK = CPR - 1;
  constexpr int RPW = 64 / CPR;
  constexpr int RPP = 4 * RPW;
  constexpr int WMT = BM / WR;
  constexpr int WNT = BN / WC;
  constexpr int FI = WMT / 16;
  constexpr int FJ = WNT / 16;
  constexpr int KK = BK / 32;
  __shared__ __align__(16) short As[2][BM * BK];
  __shared__ __align__(16) short Bs[2][BN * BK];
  const int tid = threadIdx.x;
  const int lane = tid & 63;
  const int wid = tid >> 6;
  const int wm = wid / WC, wn = wid % WC;
  const int bm = blockIdx.y * BM;
  const int bn = blockIdx.x * BN;

  const int st_r = lane / CPR;
  const int st_cs = (lane & MASK) ^ (st_r & MASK);

  const int frag_m = lane & 15;
  const int q = lane >> 4;

  auto stage = [&](int buf, int k0) {
#pragma unroll
    for (int p = 0; p < BM / RPP; ++p) {
      const bf16* g = A + (size_t)(bm + p * RPP + wid * RPW + st_r) * K + k0 + st_cs * 8;
      async_load16(g, &As[buf][(p * RPP + wid * RPW) * BK]);
    }
#pragma unroll
    for (int p = 0; p < BN / RPP; ++p) {
      const bf16* g = Bt + (size_t)(bn + p * RPP + wid * RPW + st_r) * K + k0 + st_cs * 8;
      async_load16(g, &Bs[buf][(p * RPP + wid * RPW) * BK]);
    }
  };

  f32x4 acc[FI][FJ] = {};

  stage(0, 0);
  __syncthreads();

  const int nsteps = K / BK;
  int cur = 0;
  for (int t = 0; t < nsteps; ++t) {
    // issue next-tile prefetch into the other buffer BEFORE compute
    if (t + 1 < nsteps) stage(cur ^ 1, (t + 1) * BK);

    short8 af[FI][KK], bfr[FJ][KK];
#pragma unroll
    for (int i = 0; i < FI; ++i) {
      const int m = wm * WMT + i * 16 + frag_m;
#pragma unroll
      for (int kk = 0; kk < KK; ++kk) {
        const int slot = (kk * 4 + q) ^ (m & MASK);
        af[i][kk] = *(const short8*)&As[cur][m * BK + slot * 8];
      }
    }
#pragma unroll
    for (int j = 0; j < FJ; ++j) {
      const int n = wn * WNT + j * 16 + frag_m;
#pragma unroll
      for (int kk = 0; kk < KK; ++kk) {
        const int slot = (kk * 4 + q) ^ (n & MASK);
        bfr[j][kk] = *(const short8*)&Bs[cur][n * BK + slot * 8];
      }
    }
#pragma unroll
    for (int kk = 0; kk < KK; ++kk)
#pragma unroll
      for (int i = 0; i < FI; ++i)
#pragma unroll
        for (int j = 0; j < FJ; ++j)
          acc[i][j] = __builtin_amdgcn_mfma_f32_16x16x32_bf16(af[i][kk], bfr[j][kk], acc[i][j], 0, 0, 0);

    // drains the prefetch (vmcnt) + orders LDS reuse; the prefetch had the
    // whole ds_read+MFMA phase to complete.
    __syncthreads();
    cur ^= 1;
  }

  const int col_lane = lane & 15;
  const int row_quad = q << 2;
#pragma unroll
  for (int i = 0; i < FI; ++i) {
#pragma unroll
    for (int j = 0; j < FJ; ++j) {
      int n = bn + wn * WNT + j * 16 + col_lane;
      float bj = bias[n];
#pragma unroll
      for (int r = 0; r < 4; ++r) {
        int m = bm + wm * WMT + i * 16 + row_quad + r;
        float v = acc[i][j][r] + bj;
        if (ACT == 0) v = (v >= 0.f) ? v : 0.2f * v;
        else v = fast_tanh(v);
        stf(C, (size_t)m * N + n, v);
      }
    }
  }
}

// ---------------- fallback GEMM1 (f32 A and W) — used only if ws too small
__global__ __launch_bounds__(256) void gemm_cvt(const float* __restrict__ A,
                                                const float* __restrict__ W,
                                                const float* __restrict__ bias,
                                                bf16* __restrict__ C,
                                                int M, int N, int K) {
  __shared__ __align__(16) short As[128 * 40];
  __shared__ __align__(16) short Bs[128 * 40];
  const int tid = threadIdx.x;
  const int lane = tid & 63;
  const int wave = tid >> 6;
  const int wm = wave >> 1, wn = wave & 1;
  const int bm = blockIdx.y * 128;
  const int bn = blockIdx.x * 128;
  const int a_row0 = tid >> 2;
  const int a_kcol = (tid & 3) << 3;
  const int b_ncol = (tid & 31) << 2;
  const int b_krow = (tid >> 5) << 2;
  const int frag_m = lane & 15;
  const int frag_k = (lane >> 4) << 3;

  f32x4 acc[4][4] = {};

  for (int k0 = 0; k0 < K; k0 += 32) {
#pragma unroll
    for (int c = 0; c < 2; ++c) {
      const int row = c * 64 + a_row0;
      short8 v = ld8b(A + (size_t)(bm + row) * K + k0 + a_kcol);
      *(short8*)&As[row * 40 + a_kcol] = v;
    }
    short4v bv[4];
#pragma unroll
    for (int kk = 0; kk < 4; ++kk)
      bv[kk] = ld4b(W + (size_t)(k0 + b_krow + kk) * N + bn + b_ncol);
#pragma unroll
    for (int nn = 0; nn < 4; ++nn) {
      short4v w;
      w[0] = bv[0][nn]; w[1] = bv[1][nn]; w[2] = bv[2][nn]; w[3] = bv[3][nn];
      *(short4v*)&Bs[(b_ncol + nn) * 40 + b_krow] = w;
    }
    __syncthreads();
    short8 af[4], bfr[4];
#pragma unroll
    for (int i = 0; i < 4; ++i)
      af[i] = *(const short8*)&As[(wm * 64 + i * 16 + frag_m) * 40 + frag_k];
#pragma unroll
    for (int j = 0; j < 4; ++j)
      bfr[j] = *(const short8*)&Bs[(wn * 64 + j * 16 + frag_m) * 40 + frag_k];
#pragma unroll
    for (int i = 0; i < 4; ++i)
#pragma unroll
      for (int j = 0; j < 4; ++j)
        acc[i][j] = __builtin_amdgcn_mfma_f32_16x16x32_bf16(af[i], bfr[j], acc[i][j], 0, 0, 0);
    __syncthreads();
  }

  const int col_lane = lane & 15;
  const int row_quad = (lane >> 4) << 2;
#pragma unroll
  for (int i = 0; i < 4; ++i)
#pragma unroll
    for (int j = 0; j < 4; ++j) {
      int n = bn + wn * 64 + j * 16 + col_lane;
      float bj = bias[n];
#pragma unroll
      for (int r = 0; r < 4; ++r) {
        int m = bm + wm * 64 + i * 16 + row_quad + r;
        float v = acc[i][j][r] + bj;
        v = (v >= 0.f) ? v : 0.2f * v;
        stf(C, (size_t)m * N + n, v);
      }
    }
}

// ---------------- circuit + fused d1: 1 wave per batch element.
// After full-butterfly reductions every lane holds all 24 expectation
// values; each lane then computes 2 of d1's 128 outputs directly.
__global__ __launch_bounds__(256) void circuit_wave(const float* __restrict__ enc,
                                                    const float* __restrict__ gw,
                                                    const float* __restrict__ dw1,
                                                    const float* __restrict__ db1,
                                                    bf16* __restrict__ d1out) {
  __shared__ float gsh[384];
  const int tid = threadIdx.x;
  for (int t = tid; t < 384; t += 256) gsh[t] = gw[t];
  __syncthreads();
  const int lane = tid & 63;
  const int b = blockIdx.x * 4 + (tid >> 6);

  float4 e = *(const float4*)(enc + (size_t)b * 256 + lane * 4);
  float re[4] = {e.x, e.y, e.z, e.w};
  float im[4] = {0.f, 0.f, 0.f, 0.f};
  float ss = e.x * e.x + e.y * e.y + e.z * e.z + e.w * e.w;
#pragma unroll
  for (int o = 32; o; o >>= 1) ss += __shfl_xor(ss, o, 64);
  float inv = 1.0f / fmaxf(sqrtf(ss), 1e-12f);
#pragma unroll
  for (int j = 0; j < 4; ++j) re[j] *= inv;

  for (int l = 0; l < 6; ++l) {
    for (int qq = 0; qq < 8; ++qq) {
      const float* g = &gsh[(l * 8 + qq) * 8];
      const int s = 1 << (7 - qq);
      if (s >= 4) {
        const int lm = s >> 2;
        const bool hi = (lane & lm) != 0;
        const float g0r = hi ? g[4] : g[0], g0i = hi ? g[5] : g[1];
        const float g1r = hi ? g[6] : g[2], g1i = hi ? g[7] : g[3];
#pragma unroll
        for (int j = 0; j < 4; ++j) {
          float orr = __shfl_xor(re[j], lm, 64);
          float oii = __shfl_xor(im[j], lm, 64);
          float p0r = hi ? orr : re[j], p0i = hi ? oii : im[j];
          float p1r = hi ? re[j] : orr, p1i = hi ? im[j] : oii;
          re[j] = g0r * p0r - g0i * p0i + g1r * p1r - g1i * p1i;
          im[j] = g0r * p0i + g0i * p0r + g1r * p1i + g1i * p1r;
        }
      } else {
#pragma unroll
        for (int j0 = 0; j0 < 4; ++j0) {
          if ((j0 & s) == 0) {
            int j1 = j0 | s;
            float p0r = re[j0], p0i = im[j0], p1r = re[j1], p1i = im[j1];
            re[j0] = g[0] * p0r - g[1] * p0i + g[2] * p1r - g[3] * p1i;
            im[j0] = g[0] * p0i + g[1] * p0r + g[2] * p1i + g[3] * p1r;
            re[j1] = g[4] * p0r - g[5] * p0i + g[6] * p1r - g[7] * p1i;
            im[j1] = g[4] * p0i + g[5] * p0r + g[6] * p1i + g[7] * p1r;
          }
        }
      }
    }
    const int r = l % 7 + 1;
    for (int qq = 0; qq < 8; ++qq) {
      const int sc = 1 << (7 - qq);
      const int st = 1 << (7 - ((qq + r) & 7));
      if (st >= 4) {
        const int lm = st >> 2;
        if (sc >= 4) {
          const bool ctl = (lane & (sc >> 2)) != 0;
#pragma unroll
          for (int j = 0; j < 4; ++j) {
            float orr = __shfl_xor(re[j], lm, 64);
            float oii = __shfl_xor(im[j], lm, 64);
            re[j] = ctl ? orr : re[j];
            im[j] = ctl ? oii : im[j];
          }
        } else {
#pragma unroll
          for (int j = 0; j < 4; ++j) {
            if (j & sc) {
              re[j] = __shfl_xor(re[j], lm, 64);
              im[j] = __shfl_xor(im[j], lm, 64);
            }
          }
        }
      } else {
        if (sc >= 4) {
          const bool ctl = (lane & (sc >> 2)) != 0;
#pragma unroll
          for (int j0 = 0; j0 < 4; ++j0) {
            if ((j0 & st) == 0) {
              int j1 = j0 | st;
              float t0r = re[j0], t0i = im[j0];
              float t1r = re[j1], t1i = im[j1];
              re[j0] = ctl ? t1r : t0r; im[j0] = ctl ? t1i : t0i;
              re[j1] = ctl ? t0r : t1r; im[j1] = ctl ? t0i : t1i;
            }
          }
        } else {
#pragma unroll
          for (int j0 = 0; j0 < 4; ++j0) {
            if ((j0 & sc) && (j0 & st) == 0) {
              int j1 = j0 | st;
              float tr = re[j0], ti = im[j0];
              re[j0] = re[j1]; im[j0] = im[j1];
              re[j1] = tr; im[j1] = ti;
            }
          }
        }
      }
    }
  }

  float mz[8], mx[8], my[8];
#pragma unroll
  for (int qq = 0; qq < 8; ++qq) {
    const int s = 1 << (7 - qq);
    float z = 0.f, x = 0.f, y = 0.f;
#pragma unroll
    for (int j = 0; j < 4; ++j) {
      float fr, fi;
      if (s >= 4) {
        fr = __shfl_xor(re[j], s >> 2, 64);
        fi = __shfl_xor(im[j], s >> 2, 64);
      } else {
        fr = re[j ^ s]; fi = im[j ^ s];
      }
      float prob = re[j] * re[j] + im[j] * im[j];
      int i = lane * 4 + j;
      float sg = (i & s) ? -1.f : 1.f;
      z += sg * prob;
      x += re[j] * fr + im[j] * fi;
      y += sg * (re[j] * fi - im[j] * fr);
    }
#pragma unroll
    for (int o = 32; o; o >>= 1) {
      z += __shfl_xor(z, o, 64);
      x += __shfl_xor(x, o, 64);
      y += __shfl_xor(y, o, 64);
    }
    mz[qq] = z; mx[qq] = x; my[qq] = y;
  }

  // fused d1: leaky(meas @ dw1 + db1), dw1 f32 [24][128]
#pragma unroll
  for (int half = 0; half < 2; ++half) {
    const int n = lane + half * 64;
    float acc = db1[n];
#pragma unroll
    for (int qq = 0; qq < 8; ++qq) {
      acc += mz[qq] * dw1[qq * 128 + n];
      acc += mx[qq] * dw1[(8 + qq) * 128 + n];
      acc += my[qq] * dw1[(16 + qq) * 128 + n];
    }
    acc = (acc >= 0.f) ? acc : 0.2f * acc;
    d1out[(size_t)b * 128 + n] = __float2bfloat16(acc);
  }
}

extern "C" void kernel_launch(void* const* d_in, const int* in_sizes, int n_in,
                              void* d_out, int out_size, void* d_ws, size_t ws_size,
                              hipStream_t stream) {
  (void)in_sizes; (void)n_in; (void)out_size;
  char* wsb = (char*)d_ws;
  float* gw    = (float*)(wsb + 256);
  float* biasf = (float*)(wsb + 4096);
  float* encf  = (float*)(wsb + 294912);
  bf16*  P     = (bf16*)(wsb + 4489216);
  bf16*  Q     = (bf16*)(wsb + 12877824);
  bf16*  WT    = (bf16*)(wsb + 17072128);
  bf16*  Xb    = (bf16*)(wsb + 30253056);
  const bool have_xb = ws_size >= 51224576;

  bf16* ew1t = WT + 0;
  bf16* ew2t = WT + 2621440;
  bf16* ew3t = WT + 3145728;
  bf16* dw2t = WT + 3280896;
  bf16* dw3t = WT + 3313664;
  bf16* dw4t = WT + 3444736;
  bf16* dw5t = WT + 3969024;
  float* beb1 = biasf + 0;
  float* beb2 = biasf + 1024;
  float* beb3 = biasf + 1536;
  float* bdb2 = biasf + 1920;
  float* bdb3 = biasf + 2176;
  float* bdb4 = biasf + 2688;
  float* bdb5 = biasf + 3712;

  prep_all<<<11565, 256, 0, stream>>>(
      (const float*)d_in[1], (const float*)d_in[3], (const float*)d_in[5],
      (const float*)d_in[8], (const float*)d_in[10], (const float*)d_in[12],
      (const float*)d_in[14], (const float*)d_in[16],
      (const float*)d_in[2], (const float*)d_in[4], (const float*)d_in[6],
      (const float*)d_in[9], (const float*)d_in[11], (const float*)d_in[13],
      (const float*)d_in[15], (const float*)d_in[17],
      (const float*)d_in[7], (const float*)d_in[0],
      WT, biasf, gw, Xb, have_xb ? 1 : 0);

  // ---- GEMM1: h1 = leaky(x @ ew1 + eb1)   [4096x1024, K=2560]
  if (have_xb) {
    gemm_async<128, 64, 64, 4, 1, 0, bf16><<<dim3(16, 32), 256, 0, stream>>>(
        Xb, ew1t, beb1, P, 4096, 1024, 2560);
  } else {
    gemm_cvt<<<dim3(8, 32), 256, 0, stream>>>(
        (const float*)d_in[0], (const float*)d_in[1], beb1, P, 4096, 1024, 2560);
  }

  // ---- GEMM2: h2 = leaky(h1 @ ew2 + eb2)  [4096x512, K=1024]
  gemm_async<64, 64, 64, 2, 2, 0, bf16><<<dim3(8, 64), 256, 0, stream>>>(
      P, ew2t, beb2, Q, 4096, 512, 1024);
  // ---- GEMM3: enc = tanh(h2 @ ew3 + eb3)  [4096x256, K=512] -> f32
  gemm_async<64, 64, 64, 2, 2, 1, float><<<dim3(4, 64), 256, 0, stream>>>(
      Q, ew3t, beb3, encf, 4096, 256, 512);

  // ---- circuit + fused d1 -> Q bf16 [4096][128]
  circuit_wave<<<1024, 256, 0, stream>>>(encf, gw, (const float*)d_in[8],
                                         (const float*)d_in[9], Q);

  // ---- decoder
  gemm_async<64, 64, 64, 2, 2, 0, bf16><<<dim3(4, 64), 256, 0, stream>>>(
      Q, dw2t, bdb2, P, 4096, 256, 128);
  gemm_async<64, 64, 64, 2, 2, 0, bf16><<<dim3(8, 64), 256, 0, stream>>>(
      P, dw3t, bdb3, Q, 4096, 512, 256);
  gemm_async<128, 64, 64, 4, 1, 0, bf16><<<dim3(16, 32), 256, 0, stream>>>(
      Q, dw4t, bdb4, P, 4096, 1024, 512);
  // ---- d5: out = tanh(d4 @ dw5 + db5)  [4096x2560, K=1024] -> f32
  gemm_async<128, 128, 64, 2, 2, 1, float><<<dim3(20, 32), 256, 0, stream>>>(
      P, dw5t, bdb5, (float*)d_out, 4096, 2560, 1024);
}

// Round 2
// 299.026 us; speedup vs baseline: 1.0305x; 1.0066x over previous
//
#include <hip/hip_runtime.h>
#include <hip/hip_bf16.h>

// f32-storage implementation. BK=64 async GEMM with DOUBLE-BUFFERED LDS
// (issue-early prefetch), XOR-swizzled LDS, fast-tanh epilogues.
// Circuit restructured as GEMM: U (256x256 complex, data-independent) is
// built from 256 basis-state waves inside prep_all, stored as a hi/lo
// compensated bf16 B-operand (K=768). psi = enc @ U^T runs on the matrix
// pipe; a light meas_d1 kernel computes the 24 observables + fused d1.
// ws layout (bytes):
//   [256)        gates: 384 f32
//   [4096)       biasf: 6272 f32
//   [294912)     BtU bf16 [512][768]  (have_xb)  /  encf f32 (fallback)
//   [4489216)    P     bf16 4096x1024 (h1,d2,d4)            ends 12,877,824
//   [12877824)   Q     bf16 4096x512  (h2,d1,d3)            ends 17,072,128
//   [17072128)   WT    bf16 transposed weights (13.18 MB)   ends 30,253,056
//   [30253056)   Xb    bf16 4096x2560 (x converted; GEMM1 only)
//   [30253056)   A'    bf16 4096x768 (after GEMM1 done)     ends 36,544,512
//   [36544512)   PSI   f32  4096x512                        ends 44,933,120

using bf16 = __hip_bfloat16;
typedef __attribute__((ext_vector_type(8))) short short8;
typedef __attribute__((ext_vector_type(4))) short short4v;
typedef __attribute__((ext_vector_type(4))) float f32x4;

__device__ inline void stf(float* p, size_t i, float v) { p[i] = v; }
__device__ inline void stf(bf16* p, size_t i, float v) { p[i] = __float2bfloat16(v); }

// fast tanh: ~5 VALU ops, clamped so exp stays finite (no inf/inf NaN).
__device__ inline float fast_tanh(float x) {
  x = fminf(fmaxf(x, -15.0f), 15.0f);
  float t = __expf(2.0f * x);
  return __fdividef(t - 1.0f, t + 1.0f);
}

__device__ inline short f2bs(float x) {
  bf16 h = __float2bfloat16(x);
  return *reinterpret_cast<short*>(&h);
}
__device__ inline short8 ld8b(const float* p) {
  const float4 a = ((const float4*)p)[0];
  const float4 b = ((const float4*)p)[1];
  short8 r;
  r[0] = f2bs(a.x); r[1] = f2bs(a.y); r[2] = f2bs(a.z); r[3] = f2bs(a.w);
  r[4] = f2bs(b.x); r[5] = f2bs(b.y); r[6] = f2bs(b.z); r[7] = f2bs(b.w);
  return r;
}
__device__ inline short4v ld4b(const float* p) {
  const float4 a = *(const float4*)p;
  short4v r;
  r[0] = f2bs(a.x); r[1] = f2bs(a.y); r[2] = f2bs(a.z); r[3] = f2bs(a.w);
  return r;
}

__device__ inline void async_load16(const bf16* g, short* l) {
  __builtin_amdgcn_global_load_lds(
      (const __attribute__((address_space(1))) unsigned int*)g,
      (__attribute__((address_space(3))) unsigned int*)l, 16, 0, 0);
}

// ---------------- shared 6-layer circuit body (per-wave, 4 amps/lane)
__device__ inline void run_circuit(float (&re)[4], float (&im)[4],
                                   const float* gsh, int lane) {
  for (int l = 0; l < 6; ++l) {
    for (int qq = 0; qq < 8; ++qq) {
      const float* g = &gsh[(l * 8 + qq) * 8];
      const int s = 1 << (7 - qq);
      if (s >= 4) {
        const int lm = s >> 2;
        const bool hi = (lane & lm) != 0;
        const float g0r = hi ? g[4] : g[0], g0i = hi ? g[5] : g[1];
        const float g1r = hi ? g[6] : g[2], g1i = hi ? g[7] : g[3];
#pragma unroll
        for (int j = 0; j < 4; ++j) {
          float orr = __shfl_xor(re[j], lm, 64);
          float oii = __shfl_xor(im[j], lm, 64);
          float p0r = hi ? orr : re[j], p0i = hi ? oii : im[j];
          float p1r = hi ? re[j] : orr, p1i = hi ? im[j] : oii;
          re[j] = g0r * p0r - g0i * p0i + g1r * p1r - g1i * p1i;
          im[j] = g0r * p0i + g0i * p0r + g1r * p1i + g1i * p1r;
        }
      } else {
#pragma unroll
        for (int j0 = 0; j0 < 4; ++j0) {
          if ((j0 & s) == 0) {
            int j1 = j0 | s;
            float p0r = re[j0], p0i = im[j0], p1r = re[j1], p1i = im[j1];
            re[j0] = g[0] * p0r - g[1] * p0i + g[2] * p1r - g[3] * p1i;
            im[j0] = g[0] * p0i + g[1] * p0r + g[2] * p1i + g[3] * p1r;
            re[j1] = g[4] * p0r - g[5] * p0i + g[6] * p1r - g[7] * p1i;
            im[j1] = g[4] * p0i + g[5] * p0r + g[6] * p1i + g[7] * p1r;
          }
        }
      }
    }
    const int r = l % 7 + 1;
    for (int qq = 0; qq < 8; ++qq) {
      const int sc = 1 << (7 - qq);
      const int st = 1 << (7 - ((qq + r) & 7));
      if (st >= 4) {
        const int lm = st >> 2;
        if (sc >= 4) {
          const bool ctl = (lane & (sc >> 2)) != 0;
#pragma unroll
          for (int j = 0; j < 4; ++j) {
            float orr = __shfl_xor(re[j], lm, 64);
            float oii = __shfl_xor(im[j], lm, 64);
            re[j] = ctl ? orr : re[j];
            im[j] = ctl ? oii : im[j];
          }
        } else {
#pragma unroll
          for (int j = 0; j < 4; ++j) {
            if (j & sc) {
              re[j] = __shfl_xor(re[j], lm, 64);
              im[j] = __shfl_xor(im[j], lm, 64);
            }
          }
        }
      } else {
        if (sc >= 4) {
          const bool ctl = (lane & (sc >> 2)) != 0;
#pragma unroll
          for (int j0 = 0; j0 < 4; ++j0) {
            if ((j0 & st) == 0) {
              int j1 = j0 | st;
              float t0r = re[j0], t0i = im[j0];
              float t1r = re[j1], t1i = im[j1];
              re[j0] = ctl ? t1r : t0r; im[j0] = ctl ? t1i : t0i;
              re[j1] = ctl ? t0r : t1r; im[j1] = ctl ? t0i : t1i;
            }
          }
        } else {
#pragma unroll
          for (int j0 = 0; j0 < 4; ++j0) {
            if ((j0 & sc) && (j0 & st) == 0) {
              int j1 = j0 | st;
              float tr = re[j0], ti = im[j0];
              re[j0] = re[j1]; im[j0] = im[j1];
              re[j1] = tr; im[j1] = ti;
            }
          }
        }
      }
    }
  }
}

// ---------------- prep: basis-U columns; weights -> WT bf16 [N][Kp];
// biases; gates; x -> bf16. Basis blocks are 0..63 so they launch first
// and their latency chains hide under the memory-bound rest of prep.
__global__ __launch_bounds__(256) void prep_all(
    const float* w0, const float* w1, const float* w2, const float* w3,
    const float* w4, const float* w5, const float* w6, const float* w7,
    const float* b0, const float* b1, const float* b2, const float* b3,
    const float* b4, const float* b5, const float* b6, const float* b7,
    const float* dp, const float* xf,
    bf16* __restrict__ wt, float* __restrict__ biasf, float* __restrict__ gw,
    bf16* __restrict__ xb, bf16* __restrict__ btu, int do_x) {
  int bid = blockIdx.x;
  const int tid = threadIdx.x;

  if (bid < 64) {
    // ---- basis-state circuit -> U columns, hi/lo compensated bf16
    __shared__ float gsh[384];
    if (tid < 48) {
      float phi = dp[tid * 3 + 0], theta = dp[tid * 3 + 1], omega = dp[tid * 3 + 2];
      float c = cosf(0.5f * theta), s = sinf(0.5f * theta);
      float a = 0.5f * (phi + omega), d = 0.5f * (phi - omega);
      float ca = cosf(a), sa = sinf(a), cd = cosf(d), sd = sinf(d);
      float* o = &gsh[tid * 8];
      o[0] =  ca * c; o[1] = -sa * c;
      o[2] = -cd * s; o[3] = -sd * s;
      o[4] =  cd * s; o[5] = -sd * s;
      o[6] =  ca * c; o[7] =  sa * c;
    }
    __syncthreads();
    const int lane = tid & 63;
    const int col = bid * 4 + (tid >> 6);   // basis column k in [0,256)
    float re[4], im[4];
#pragma unroll
    for (int j = 0; j < 4; ++j) { re[j] = (lane * 4 + j == col) ? 1.f : 0.f; im[j] = 0.f; }
    run_circuit(re, im, gsh, lane);
    // Bt row n pairs with A' = [enc_hi | enc_lo | enc_hi]:
    //   seg0 = U_hi, seg1 = U_hi, seg2 = U_lo
#pragma unroll
    for (int j = 0; j < 4; ++j) {
      int n = lane * 4 + j;
      {
        bf16 h = __float2bfloat16(re[j]);
        float lo = re[j] - __bfloat162float(h);
        size_t base = (size_t)n * 768 + col;
        btu[base] = h; btu[base + 256] = h; btu[base + 512] = __float2bfloat16(lo);
      }
      {
        bf16 h = __float2bfloat16(im[j]);
        float lo = im[j] - __bfloat162float(h);
        size_t base = (size_t)(256 + n) * 768 + col;
        btu[base] = h; btu[base + 256] = h; btu[base + 512] = __float2bfloat16(lo);
      }
    }
    return;
  }
  bid -= 64;

  const int Ks[8]  = {2560, 1024, 512, 24, 128, 256, 512, 1024};
  const int Ns[8]  = {1024, 512, 256, 128, 256, 512, 1024, 2560};
  const int cum[8] = {2560, 3072, 3200, 3204, 3236, 3364, 3876, 6436};
  const long wto[8] = {0, 2621440, 3145728, 3276800, 3280896, 3313664, 3444736, 3969024};
  const float* Wp[8] = {w0, w1, w2, w3, w4, w5, w6, w7};
  const float* Bp[8] = {b0, b1, b2, b3, b4, b5, b6, b7};
  const int boff[8] = {0, 1024, 1536, 1792, 1920, 2176, 2688, 3712};

  if (bid < 6436) {
    int t = 0;
    while (bid >= cum[t]) t++;
    int base = t ? cum[t - 1] : 0;
    int local = bid - base;
    int K = Ks[t], N = Ns[t];
    int tk = (K + 31) >> 5;
    int kt = local % tk, nt = local / tk;
    int Kp = tk << 5;
    __shared__ short tile[32][33];
    int r = tid >> 3, c4 = (tid & 7) << 2;
    int gk = kt * 32 + r, gn = nt * 32 + c4;
    short4v v;
    if (gk < K) v = ld4b(Wp[t] + (size_t)gk * N + gn);
    else { v[0] = 0; v[1] = 0; v[2] = 0; v[3] = 0; }
    tile[r][c4] = v[0]; tile[r][c4 + 1] = v[1]; tile[r][c4 + 2] = v[2]; tile[r][c4 + 3] = v[3];
    __syncthreads();
    int n = tid >> 3, k4 = (tid & 7) << 2;
    short4v o;
    o[0] = tile[k4][n]; o[1] = tile[k4 + 1][n]; o[2] = tile[k4 + 2][n]; o[3] = tile[k4 + 3][n];
    *(short4v*)&wt[wto[t] + (size_t)(nt * 32 + n) * Kp + kt * 32 + k4] = o;
  } else if (bid < 6444) {
    int b = bid - 6436;
    int nb = Ns[b];
    for (int t2 = tid; t2 < nb; t2 += 256)
      biasf[boff[b] + t2] = Bp[b][t2];
  } else if (bid == 6444) {
    int g = tid;
    if (g < 48) {
      float phi = dp[g * 3 + 0], theta = dp[g * 3 + 1], omega = dp[g * 3 + 2];
      float c = cosf(0.5f * theta), s = sinf(0.5f * theta);
      float a = 0.5f * (phi + omega), d = 0.5f * (phi - omega);
      float ca = cosf(a), sa = sinf(a), cd = cosf(d), sd = sinf(d);
      float* o = gw + g * 8;
      o[0] =  ca * c; o[1] = -sa * c;
      o[2] = -cd * s; o[3] = -sd * s;
      o[4] =  cd * s; o[5] = -sd * s;
      o[6] =  ca * c; o[7] =  sa * c;
    }
  } else if (do_x) {
    long i = ((long)(bid - 6445) * 256 + tid) * 8;
    if (i < 10485760L) {
      short8 v = ld8b(xf + i);
      *(short8*)((short*)xb + i) = v;
    }
  }
}

// ---------------- async MFMA GEMM: C = act(A @ Bt^T + bias)
// Double-buffered LDS, issue-early prefetch. XOR-swizzled chunk layout.
// ACT: 0=leaky, 1=tanh, 2=identity no-bias, 3=tanh + hi/lo/hi triple store
//      (A' builder: C is bf16 [M][768], n in [0,256)).
template <int BM, int BN, int BK, int WR, int WC, int ACT, typename TC>
__global__ __launch_bounds__(256) void gemm_async(const bf16* __restrict__ A,
                                                  const bf16* __restrict__ Bt,
                                                  const float* __restrict__ bias,
                                                  TC* __restrict__ C,
                                                  int M, int N, int K) {
  constexpr int CPR = BK / 8;
  constexpr int MASK = CPR - 1;
  constexpr int RPW = 64 / CPR;
  constexpr int RPP = 4 * RPW;
  constexpr int WMT = BM / WR;
  constexpr int WNT = BN / WC;
  constexpr int FI = WMT / 16;
  constexpr int FJ = WNT / 16;
  constexpr int KK = BK / 32;
  __shared__ __align__(16) short As[2][BM * BK];
  __shared__ __align__(16) short Bs[2][BN * BK];
  const int tid = threadIdx.x;
  const int lane = tid & 63;
  const int wid = tid >> 6;
  const int wm = wid / WC, wn = wid % WC;
  const int bm = blockIdx.y * BM;
  const int bn = blockIdx.x * BN;

  const int st_r = lane / CPR;
  const int st_cs = (lane & MASK) ^ (st_r & MASK);

  const int frag_m = lane & 15;
  const int q = lane >> 4;

  auto stage = [&](int buf, int k0) {
#pragma unroll
    for (int p = 0; p < BM / RPP; ++p) {
      const bf16* g = A + (size_t)(bm + p * RPP + wid * RPW + st_r) * K + k0 + st_cs * 8;
      async_load16(g, &As[buf][(p * RPP + wid * RPW) * BK]);
    }
#pragma unroll
    for (int p = 0; p < BN / RPP; ++p) {
      const bf16* g = Bt + (size_t)(bn + p * RPP + wid * RPW + st_r) * K + k0 + st_cs * 8;
      async_load16(g, &Bs[buf][(p * RPP + wid * RPW) * BK]);
    }
  };

  f32x4 acc[FI][FJ] = {};

  stage(0, 0);
  __syncthreads();

  const int nsteps = K / BK;
  int cur = 0;
  for (int t = 0; t < nsteps; ++t) {
    if (t + 1 < nsteps) stage(cur ^ 1, (t + 1) * BK);

    short8 af[FI][KK], bfr[FJ][KK];
#pragma unroll
    for (int i = 0; i < FI; ++i) {
      const int m = wm * WMT + i * 16 + frag_m;
#pragma unroll
      for (int kk = 0; kk < KK; ++kk) {
        const int slot = (kk * 4 + q) ^ (m & MASK);
        af[i][kk] = *(const short8*)&As[cur][m * BK + slot * 8];
      }
    }
#pragma unroll
    for (int j = 0; j < FJ; ++j) {
      const int n = wn * WNT + j * 16 + frag_m;
#pragma unroll
      for (int kk = 0; kk < KK; ++kk) {
        const int slot = (kk * 4 + q) ^ (n & MASK);
        bfr[j][kk] = *(const short8*)&Bs[cur][n * BK + slot * 8];
      }
    }
#pragma unroll
    for (int kk = 0; kk < KK; ++kk)
#pragma unroll
      for (int i = 0; i < FI; ++i)
#pragma unroll
        for (int j = 0; j < FJ; ++j)
          acc[i][j] = __builtin_amdgcn_mfma_f32_16x16x32_bf16(af[i][kk], bfr[j][kk], acc[i][j], 0, 0, 0);

    __syncthreads();
    cur ^= 1;
  }

  const int col_lane = lane & 15;
  const int row_quad = q << 2;
#pragma unroll
  for (int i = 0; i < FI; ++i) {
#pragma unroll
    for (int j = 0; j < FJ; ++j) {
      int n = bn + wn * WNT + j * 16 + col_lane;
      float bj = (ACT == 2) ? 0.f : bias[n];
#pragma unroll
      for (int r = 0; r < 4; ++r) {
        int m = bm + wm * WMT + i * 16 + row_quad + r;
        float v = acc[i][j][r] + bj;
        if (ACT == 0) {
          v = (v >= 0.f) ? v : 0.2f * v;
          stf(C, (size_t)m * N + n, v);
        } else if (ACT == 1) {
          stf(C, (size_t)m * N + n, fast_tanh(v));
        } else if (ACT == 2) {
          stf(C, (size_t)m * N + n, v);
        } else {
          float tv = fast_tanh(v);
          bf16 h = __float2bfloat16(tv);
          float lo = tv - __bfloat162float(h);
          size_t base = (size_t)m * 768 + n;
          ((bf16*)C)[base] = h;
          ((bf16*)C)[base + 256] = __float2bfloat16(lo);
          ((bf16*)C)[base + 512] = h;
        }
      }
    }
  }
}

// ---------------- fallback GEMM1 (f32 A and W) — used only if ws too small
__global__ __launch_bounds__(256) void gemm_cvt(const float* __restrict__ A,
                                                const float* __restrict__ W,
                                                const float* __restrict__ bias,
                                                bf16* __restrict__ C,
                                                int M, int N, int K) {
  __shared__ __align__(16) short As[128 * 40];
  __shared__ __align__(16) short Bs[128 * 40];
  const int tid = threadIdx.x;
  const int lane = tid & 63;
  const int wave = tid >> 6;
  const int wm = wave >> 1, wn = wave & 1;
  const int bm = blockIdx.y * 128;
  const int bn = blockIdx.x * 128;
  const int a_row0 = tid >> 2;
  const int a_kcol = (tid & 3) << 3;
  const int b_ncol = (tid & 31) << 2;
  const int b_krow = (tid >> 5) << 2;
  const int frag_m = lane & 15;
  const int frag_k = (lane >> 4) << 3;

  f32x4 acc[4][4] = {};

  for (int k0 = 0; k0 < K; k0 += 32) {
#pragma unroll
    for (int c = 0; c < 2; ++c) {
      const int row = c * 64 + a_row0;
      short8 v = ld8b(A + (size_t)(bm + row) * K + k0 + a_kcol);
      *(short8*)&As[row * 40 + a_kcol] = v;
    }
    short4v bv[4];
#pragma unroll
    for (int kk = 0; kk < 4; ++kk)
      bv[kk] = ld4b(W + (size_t)(k0 + b_krow + kk) * N + bn + b_ncol);
#pragma unroll
    for (int nn = 0; nn < 4; ++nn) {
      short4v w;
      w[0] = bv[0][nn]; w[1] = bv[1][nn]; w[2] = bv[2][nn]; w[3] = bv[3][nn];
      *(short4v*)&Bs[(b_ncol + nn) * 40 + b_krow] = w;
    }
    __syncthreads();
    short8 af[4], bfr[4];
#pragma unroll
    for (int i = 0; i < 4; ++i)
      af[i] = *(const short8*)&As[(wm * 64 + i * 16 + frag_m) * 40 + frag_k];
#pragma unroll
    for (int j = 0; j < 4; ++j)
      bfr[j] = *(const short8*)&Bs[(wn * 64 + j * 16 + frag_m) * 40 + frag_k];
#pragma unroll
    for (int i = 0; i < 4; ++i)
#pragma unroll
      for (int j = 0; j < 4; ++j)
        acc[i][j] = __builtin_amdgcn_mfma_f32_16x16x32_bf16(af[i], bfr[j], acc[i][j], 0, 0, 0);
    __syncthreads();
  }

  const int col_lane = lane & 15;
  const int row_quad = (lane >> 4) << 2;
#pragma unroll
  for (int i = 0; i < 4; ++i)
#pragma unroll
    for (int j = 0; j < 4; ++j) {
      int n = bn + wn * 64 + j * 16 + col_lane;
      float bj = bias[n];
#pragma unroll
      for (int r = 0; r < 4; ++r) {
        int m = bm + wm * 64 + i * 16 + row_quad + r;
        float v = acc[i][j][r] + bj;
        v = (v >= 0.f) ? v : 0.2f * v;
        stf(C, (size_t)m * N + n, v);
      }
    }
}

// ---------------- meas + fused d1 from PSI (have_xb fast path).
// PSI f32 [4096][512]: cols 0..255 = Re(p), 256..511 = Im(p), p = U @ enc
// (unnormalized). meas = quadratic_forms(p) / ||p||^2.
__global__ __launch_bounds__(256) void meas_d1(const float* __restrict__ PSI,
                                               const float* __restrict__ dw1,
                                               const float* __restrict__ db1,
                                               bf16* __restrict__ d1out) {
  const int tid = threadIdx.x;
  const int lane = tid & 63;
  const int b = blockIdx.x * 4 + (tid >> 6);

  const float* pp = PSI + (size_t)b * 512;
  float4 ar = *(const float4*)(pp + lane * 4);
  float4 ai = *(const float4*)(pp + 256 + lane * 4);
  float re[4] = {ar.x, ar.y, ar.z, ar.w};
  float im[4] = {ai.x, ai.y, ai.z, ai.w};

  float ss = 0.f;
#pragma unroll
  for (int j = 0; j < 4; ++j) ss += re[j] * re[j] + im[j] * im[j];
#pragma unroll
  for (int o = 32; o; o >>= 1) ss += __shfl_xor(ss, o, 64);
  const float inv = 1.0f / fmaxf(ss, 1e-24f);

  float mz[8], mx[8], my[8];
#pragma unroll
  for (int qq = 0; qq < 8; ++qq) {
    const int s = 1 << (7 - qq);
    float z = 0.f, x = 0.f, y = 0.f;
#pragma unroll
    for (int j = 0; j < 4; ++j) {
      float fr, fi;
      if (s >= 4) {
        fr = __shfl_xor(re[j], s >> 2, 64);
        fi = __shfl_xor(im[j], s >> 2, 64);
      } else {
        fr = re[j ^ s]; fi = im[j ^ s];
      }
      float prob = re[j] * re[j] + im[j] * im[j];
      int i = lane * 4 + j;
      float sg = (i & s) ? -1.f : 1.f;
      z += sg * prob;
      x += re[j] * fr + im[j] * fi;
      y += sg * (re[j] * fi - im[j] * fr);
    }
#pragma unroll
    for (int o = 32; o; o >>= 1) {
      z += __shfl_xor(z, o, 64);
      x += __shfl_xor(x, o, 64);
      y += __shfl_xor(y, o, 64);
    }
    mz[qq] = z * inv; mx[qq] = x * inv; my[qq] = y * inv;
  }

  // fused d1: leaky(meas @ dw1 + db1), dw1 f32 [24][128]
#pragma unroll
  for (int half = 0; half < 2; ++half) {
    const int n = lane + half * 64;
    float acc = db1[n];
#pragma unroll
    for (int qq = 0; qq < 8; ++qq) {
      acc += mz[qq] * dw1[qq * 128 + n];
      acc += mx[qq] * dw1[(8 + qq) * 128 + n];
      acc += my[qq] * dw1[(16 + qq) * 128 + n];
    }
    acc = (acc >= 0.f) ? acc : 0.2f * acc;
    d1out[(size_t)b * 128 + n] = __float2bfloat16(acc);
  }
}

// ---------------- legacy circuit + fused d1 (fallback when !have_xb)
__global__ __launch_bounds__(256) void circuit_wave(const float* __restrict__ enc,
                                                    const float* __restrict__ gw,
                                                    const float* __restrict__ dw1,
                                                    const float* __restrict__ db1,
                                                    bf16* __restrict__ d1out) {
  __shared__ float gsh[384];
  const int tid = threadIdx.x;
  for (int t = tid; t < 384; t += 256) gsh[t] = gw[t];
  __syncthreads();
  const int lane = tid & 63;
  const int b = blockIdx.x * 4 + (tid >> 6);

  float4 e = *(const float4*)(enc + (size_t)b * 256 + lane * 4);
  float re[4] = {e.x, e.y, e.z, e.w};
  float im[4] = {0.f, 0.f, 0.f, 0.f};
  float ss = e.x * e.x + e.y * e.y + e.z * e.z + e.w * e.w;
#pragma unroll
  for (int o = 32; o; o >>= 1) ss += __shfl_xor(ss, o, 64);
  float inv = 1.0f / fmaxf(sqrtf(ss), 1e-12f);
#pragma unroll
  for (int j = 0; j < 4; ++j) re[j] *= inv;

  run_circuit(re, im, gsh, lane);

  float mz[8], mx[8], my[8];
#pragma unroll
  for (int qq = 0; qq < 8; ++qq) {
    const int s = 1 << (7 - qq);
    float z = 0.f, x = 0.f, y = 0.f;
#pragma unroll
    for (int j = 0; j < 4; ++j) {
      float fr, fi;
      if (s >= 4) {
        fr = __shfl_xor(re[j], s >> 2, 64);
        fi = __shfl_xor(im[j], s >> 2, 64);
      } else {
        fr = re[j ^ s]; fi = im[j ^ s];
      }
      float prob = re[j] * re[j] + im[j] * im[j];
      int i = lane * 4 + j;
      float sg = (i & s) ? -1.f : 1.f;
      z += sg * prob;
      x += re[j] * fr + im[j] * fi;
      y += sg * (re[j] * fi - im[j] * fr);
    }
#pragma unroll
    for (int o = 32; o; o >>= 1) {
      z += __shfl_xor(z, o, 64);
      x += __shfl_xor(x, o, 64);
      y += __shfl_xor(y, o, 64);
    }
    mz[qq] = z; mx[qq] = x; my[qq] = y;
  }

#pragma unroll
  for (int half = 0; half < 2; ++half) {
    const int n = lane + half * 64;
    float acc = db1[n];
#pragma unroll
    for (int qq = 0; qq < 8; ++qq) {
      acc += mz[qq] * dw1[qq * 128 + n];
      acc += mx[qq] * dw1[(8 + qq) * 128 + n];
      acc += my[qq] * dw1[(16 + qq) * 128 + n];
    }
    acc = (acc >= 0.f) ? acc : 0.2f * acc;
    d1out[(size_t)b * 128 + n] = __float2bfloat16(acc);
  }
}

extern "C" void kernel_launch(void* const* d_in, const int* in_sizes, int n_in,
                              void* d_out, int out_size, void* d_ws, size_t ws_size,
                              hipStream_t stream) {
  (void)in_sizes; (void)n_in; (void)out_size;
  char* wsb = (char*)d_ws;
  float* gw    = (float*)(wsb + 256);
  float* biasf = (float*)(wsb + 4096);
  float* encf  = (float*)(wsb + 294912);       // fallback only
  bf16*  BtU   = (bf16*)(wsb + 294912);        // have_xb only (overlays encf)
  bf16*  P     = (bf16*)(wsb + 4489216);
  bf16*  Q     = (bf16*)(wsb + 12877824);
  bf16*  WT    = (bf16*)(wsb + 17072128);
  bf16*  Xb    = (bf16*)(wsb + 30253056);
  bf16*  Ap    = (bf16*)(wsb + 30253056);      // A' overlays Xb after GEMM1
  float* PSI   = (float*)(wsb + 36544512);
  const bool have_xb = ws_size >= 51224576;

  bf16* ew1t = WT + 0;
  bf16* ew2t = WT + 2621440;
  bf16* ew3t = WT + 3145728;
  bf16* dw2t = WT + 3280896;
  bf16* dw3t = WT + 3313664;
  bf16* dw4t = WT + 3444736;
  bf16* dw5t = WT + 3969024;
  float* beb1 = biasf + 0;
  float* beb2 = biasf + 1024;
  float* beb3 = biasf + 1536;
  float* bdb2 = biasf + 1920;
  float* bdb3 = biasf + 2176;
  float* bdb4 = biasf + 2688;
  float* bdb5 = biasf + 3712;

  prep_all<<<11629, 256, 0, stream>>>(
      (const float*)d_in[1], (const float*)d_in[3], (const float*)d_in[5],
      (const float*)d_in[8], (const float*)d_in[10], (const float*)d_in[12],
      (const float*)d_in[14], (const float*)d_in[16],
      (const float*)d_in[2], (const float*)d_in[4], (const float*)d_in[6],
      (const float*)d_in[9], (const float*)d_in[11], (const float*)d_in[13],
      (const float*)d_in[15], (const float*)d_in[17],
      (const float*)d_in[7], (const float*)d_in[0],
      WT, biasf, gw, Xb, BtU, have_xb ? 1 : 0);

  // ---- GEMM1: h1 = leaky(x @ ew1 + eb1)   [4096x1024, K=2560]
  if (have_xb) {
    gemm_async<128, 64, 64, 4, 1, 0, bf16><<<dim3(16, 32), 256, 0, stream>>>(
        Xb, ew1t, beb1, P, 4096, 1024, 2560);
  } else {
    gemm_cvt<<<dim3(8, 32), 256, 0, stream>>>(
        (const float*)d_in[0], (const float*)d_in[1], beb1, P, 4096, 1024, 2560);
  }

  // ---- GEMM2: h2 = leaky(h1 @ ew2 + eb2)  [4096x512, K=1024]
  gemm_async<64, 64, 64, 2, 2, 0, bf16><<<dim3(8, 64), 256, 0, stream>>>(
      P, ew2t, beb2, Q, 4096, 512, 1024);

  if (have_xb) {
    // ---- GEMM3: A' = hi/lo/hi(tanh(h2 @ ew3 + eb3))  [4096x768 bf16]
    gemm_async<64, 64, 64, 2, 2, 3, bf16><<<dim3(4, 64), 256, 0, stream>>>(
        Q, ew3t, beb3, Ap, 4096, 256, 512);
    // ---- PSI = A' @ BtU^T  [4096x512 f32, K=768] (compensated bf16 GEMM)
    gemm_async<64, 64, 64, 2, 2, 2, float><<<dim3(8, 64), 256, 0, stream>>>(
        Ap, BtU, beb3 /*unused*/, PSI, 4096, 512, 768);
    // ---- measurements + fused d1 -> Q bf16 [4096][128]
    meas_d1<<<1024, 256, 0, stream>>>(PSI, (const float*)d_in[8],
                                      (const float*)d_in[9], Q);
  } else {
    // ---- GEMM3: enc = tanh(h2 @ ew3 + eb3)  [4096x256 f32]
    gemm_async<64, 64, 64, 2, 2, 1, float><<<dim3(4, 64), 256, 0, stream>>>(
        Q, ew3t, beb3, encf, 4096, 256, 512);
    circuit_wave<<<1024, 256, 0, stream>>>(encf, gw, (const float*)d_in[8],
                                           (const float*)d_in[9], Q);
  }

  // ---- decoder
  gemm_async<64, 64, 64, 2, 2, 0, bf16><<<dim3(4, 64), 256, 0, stream>>>(
      Q, dw2t, bdb2, P, 4096, 256, 128);
  gemm_async<64, 64, 64, 2, 2, 0, bf16><<<dim3(8, 64), 256, 0, stream>>>(
      P, dw3t, bdb3, Q, 4096, 512, 256);
  gemm_async<128, 64, 64, 4, 1, 0, bf16><<<dim3(16, 32), 256, 0, stream>>>(
      Q, dw4t, bdb4, P, 4096, 1024, 512);
  // ---- d5: out = tanh(d4 @ dw5 + db5)  [4096x2560, K=1024] -> f32
  gemm_async<128, 128, 64, 2, 2, 1, float><<<dim3(20, 32), 256, 0, stream>>>(
      P, dw5t, bdb5, (float*)d_out, 4096, 2560, 1024);
}

// Round 3
// 276.509 us; speedup vs baseline: 1.1144x; 1.0814x over previous
//
#include <hip/hip_runtime.h>
#include <hip/hip_bf16.h>

// f32-storage implementation. BK=64 async GEMM with 2-DEEP counted-vmcnt
// pipeline (T3+T4: raw s_barrier, never vmcnt(0) in steady state),
// XOR-swizzled LDS, fast-tanh epilogues.
// Circuit restructured as GEMM: U (256x256 complex, data-independent) is
// built from 256 basis-state waves inside prep_all, stored as a hi/lo
// compensated bf16 B-operand (K=768). psi = enc @ U^T runs on the matrix
// pipe; a light meas_d1 kernel computes the 24 observables + fused d1.
// ws layout (bytes):
//   [256)        gates: 384 f32
//   [4096)       biasf: 6272 f32
//   [294912)     BtU bf16 [512][768]  (have_xb)  /  encf f32 (fallback)
//   [4489216)    P     bf16 4096x1024 (h1,d2,d4)            ends 12,877,824
//   [12877824)   Q     bf16 4096x512  (h2,d1,d3)            ends 17,072,128
//   [17072128)   WT    bf16 transposed weights (13.18 MB)   ends 30,253,056
//   [30253056)   Xb    bf16 4096x2560 (x converted; GEMM1 only)
//   [30253056)   A'    bf16 4096x768 (after GEMM1 done)     ends 36,544,512
//   [36544512)   PSI   f32  4096x512                        ends 44,933,120

using bf16 = __hip_bfloat16;
typedef __attribute__((ext_vector_type(8))) short short8;
typedef __attribute__((ext_vector_type(4))) short short4v;
typedef __attribute__((ext_vector_type(4))) float f32x4;

__device__ inline void stf(float* p, size_t i, float v) { p[i] = v; }
__device__ inline void stf(bf16* p, size_t i, float v) { p[i] = __float2bfloat16(v); }

// fast tanh: ~5 VALU ops, clamped so exp stays finite (no inf/inf NaN).
__device__ inline float fast_tanh(float x) {
  x = fminf(fmaxf(x, -15.0f), 15.0f);
  float t = __expf(2.0f * x);
  return __fdividef(t - 1.0f, t + 1.0f);
}

__device__ inline short f2bs(float x) {
  bf16 h = __float2bfloat16(x);
  return *reinterpret_cast<short*>(&h);
}
__device__ inline short8 ld8b(const float* p) {
  const float4 a = ((const float4*)p)[0];
  const float4 b = ((const float4*)p)[1];
  short8 r;
  r[0] = f2bs(a.x); r[1] = f2bs(a.y); r[2] = f2bs(a.z); r[3] = f2bs(a.w);
  r[4] = f2bs(b.x); r[5] = f2bs(b.y); r[6] = f2bs(b.z); r[7] = f2bs(b.w);
  return r;
}
__device__ inline short4v ld4b(const float* p) {
  const float4 a = *(const float4*)p;
  short4v r;
  r[0] = f2bs(a.x); r[1] = f2bs(a.y); r[2] = f2bs(a.z); r[3] = f2bs(a.w);
  return r;
}

__device__ inline void async_load16(const bf16* g, short* l) {
  __builtin_amdgcn_global_load_lds(
      (const __attribute__((address_space(1))) unsigned int*)g,
      (__attribute__((address_space(3))) unsigned int*)l, 16, 0, 0);
}

// ---------------- shared 6-layer circuit body (per-wave, 4 amps/lane)
__device__ inline void run_circuit(float (&re)[4], float (&im)[4],
                                   const float* gsh, int lane) {
  for (int l = 0; l < 6; ++l) {
    for (int qq = 0; qq < 8; ++qq) {
      const float* g = &gsh[(l * 8 + qq) * 8];
      const int s = 1 << (7 - qq);
      if (s >= 4) {
        const int lm = s >> 2;
        const bool hi = (lane & lm) != 0;
        const float g0r = hi ? g[4] : g[0], g0i = hi ? g[5] : g[1];
        const float g1r = hi ? g[6] : g[2], g1i = hi ? g[7] : g[3];
#pragma unroll
        for (int j = 0; j < 4; ++j) {
          float orr = __shfl_xor(re[j], lm, 64);
          float oii = __shfl_xor(im[j], lm, 64);
          float p0r = hi ? orr : re[j], p0i = hi ? oii : im[j];
          float p1r = hi ? re[j] : orr, p1i = hi ? im[j] : oii;
          re[j] = g0r * p0r - g0i * p0i + g1r * p1r - g1i * p1i;
          im[j] = g0r * p0i + g0i * p0r + g1r * p1i + g1i * p1r;
        }
      } else {
#pragma unroll
        for (int j0 = 0; j0 < 4; ++j0) {
          if ((j0 & s) == 0) {
            int j1 = j0 | s;
            float p0r = re[j0], p0i = im[j0], p1r = re[j1], p1i = im[j1];
            re[j0] = g[0] * p0r - g[1] * p0i + g[2] * p1r - g[3] * p1i;
            im[j0] = g[0] * p0i + g[1] * p0r + g[2] * p1i + g[3] * p1r;
            re[j1] = g[4] * p0r - g[5] * p0i + g[6] * p1r - g[7] * p1i;
            im[j1] = g[4] * p0i + g[5] * p0r + g[6] * p1i + g[7] * p1r;
          }
        }
      }
    }
    const int r = l % 7 + 1;
    for (int qq = 0; qq < 8; ++qq) {
      const int sc = 1 << (7 - qq);
      const int st = 1 << (7 - ((qq + r) & 7));
      if (st >= 4) {
        const int lm = st >> 2;
        if (sc >= 4) {
          const bool ctl = (lane & (sc >> 2)) != 0;
#pragma unroll
          for (int j = 0; j < 4; ++j) {
            float orr = __shfl_xor(re[j], lm, 64);
            float oii = __shfl_xor(im[j], lm, 64);
            re[j] = ctl ? orr : re[j];
            im[j] = ctl ? oii : im[j];
          }
        } else {
#pragma unroll
          for (int j = 0; j < 4; ++j) {
            if (j & sc) {
              re[j] = __shfl_xor(re[j], lm, 64);
              im[j] = __shfl_xor(im[j], lm, 64);
            }
          }
        }
      } else {
        if (sc >= 4) {
          const bool ctl = (lane & (sc >> 2)) != 0;
#pragma unroll
          for (int j0 = 0; j0 < 4; ++j0) {
            if ((j0 & st) == 0) {
              int j1 = j0 | st;
              float t0r = re[j0], t0i = im[j0];
              float t1r = re[j1], t1i = im[j1];
              re[j0] = ctl ? t1r : t0r; im[j0] = ctl ? t1i : t0i;
              re[j1] = ctl ? t0r : t1r; im[j1] = ctl ? t0i : t1i;
            }
          }
        } else {
#pragma unroll
          for (int j0 = 0; j0 < 4; ++j0) {
            if ((j0 & sc) && (j0 & st) == 0) {
              int j1 = j0 | st;
              float tr = re[j0], ti = im[j0];
              re[j0] = re[j1]; im[j0] = im[j1];
              re[j1] = tr; im[j1] = ti;
            }
          }
        }
      }
    }
  }
}

// ---------------- prep: basis-U columns; weights -> WT bf16 [N][Kp];
// biases; gates; x -> bf16. Basis blocks are 0..63 so they launch first
// and their latency chains hide under the memory-bound rest of prep.
__global__ __launch_bounds__(256) void prep_all(
    const float* w0, const float* w1, const float* w2, const float* w3,
    const float* w4, const float* w5, const float* w6, const float* w7,
    const float* b0, const float* b1, const float* b2, const float* b3,
    const float* b4, const float* b5, const float* b6, const float* b7,
    const float* dp, const float* xf,
    bf16* __restrict__ wt, float* __restrict__ biasf, float* __restrict__ gw,
    bf16* __restrict__ xb, bf16* __restrict__ btu, int do_x) {
  int bid = blockIdx.x;
  const int tid = threadIdx.x;

  if (bid < 64) {
    // ---- basis-state circuit -> U columns, hi/lo compensated bf16
    __shared__ float gsh[384];
    if (tid < 48) {
      float phi = dp[tid * 3 + 0], theta = dp[tid * 3 + 1], omega = dp[tid * 3 + 2];
      float c = cosf(0.5f * theta), s = sinf(0.5f * theta);
      float a = 0.5f * (phi + omega), d = 0.5f * (phi - omega);
      float ca = cosf(a), sa = sinf(a), cd = cosf(d), sd = sinf(d);
      float* o = &gsh[tid * 8];
      o[0] =  ca * c; o[1] = -sa * c;
      o[2] = -cd * s; o[3] = -sd * s;
      o[4] =  cd * s; o[5] = -sd * s;
      o[6] =  ca * c; o[7] =  sa * c;
    }
    __syncthreads();
    const int lane = tid & 63;
    const int col = bid * 4 + (tid >> 6);   // basis column k in [0,256)
    float re[4], im[4];
#pragma unroll
    for (int j = 0; j < 4; ++j) { re[j] = (lane * 4 + j == col) ? 1.f : 0.f; im[j] = 0.f; }
    run_circuit(re, im, gsh, lane);
    // Bt row n pairs with A' = [enc_hi | enc_lo | enc_hi]:
    //   seg0 = U_hi, seg1 = U_hi, seg2 = U_lo
#pragma unroll
    for (int j = 0; j < 4; ++j) {
      int n = lane * 4 + j;
      {
        bf16 h = __float2bfloat16(re[j]);
        float lo = re[j] - __bfloat162float(h);
        size_t base = (size_t)n * 768 + col;
        btu[base] = h; btu[base + 256] = h; btu[base + 512] = __float2bfloat16(lo);
      }
      {
        bf16 h = __float2bfloat16(im[j]);
        float lo = im[j] - __bfloat162float(h);
        size_t base = (size_t)(256 + n) * 768 + col;
        btu[base] = h; btu[base + 256] = h; btu[base + 512] = __float2bfloat16(lo);
      }
    }
    return;
  }
  bid -= 64;

  const int Ks[8]  = {2560, 1024, 512, 24, 128, 256, 512, 1024};
  const int Ns[8]  = {1024, 512, 256, 128, 256, 512, 1024, 2560};
  const int cum[8] = {2560, 3072, 3200, 3204, 3236, 3364, 3876, 6436};
  const long wto[8] = {0, 2621440, 3145728, 3276800, 3280896, 3313664, 3444736, 3969024};
  const float* Wp[8] = {w0, w1, w2, w3, w4, w5, w6, w7};
  const float* Bp[8] = {b0, b1, b2, b3, b4, b5, b6, b7};
  const int boff[8] = {0, 1024, 1536, 1792, 1920, 2176, 2688, 3712};

  if (bid < 6436) {
    int t = 0;
    while (bid >= cum[t]) t++;
    int base = t ? cum[t - 1] : 0;
    int local = bid - base;
    int K = Ks[t], N = Ns[t];
    int tk = (K + 31) >> 5;
    int kt = local % tk, nt = local / tk;
    int Kp = tk << 5;
    __shared__ short tile[32][33];
    int r = tid >> 3, c4 = (tid & 7) << 2;
    int gk = kt * 32 + r, gn = nt * 32 + c4;
    short4v v;
    if (gk < K) v = ld4b(Wp[t] + (size_t)gk * N + gn);
    else { v[0] = 0; v[1] = 0; v[2] = 0; v[3] = 0; }
    tile[r][c4] = v[0]; tile[r][c4 + 1] = v[1]; tile[r][c4 + 2] = v[2]; tile[r][c4 + 3] = v[3];
    __syncthreads();
    int n = tid >> 3, k4 = (tid & 7) << 2;
    short4v o;
    o[0] = tile[k4][n]; o[1] = tile[k4 + 1][n]; o[2] = tile[k4 + 2][n]; o[3] = tile[k4 + 3][n];
    *(short4v*)&wt[wto[t] + (size_t)(nt * 32 + n) * Kp + kt * 32 + k4] = o;
  } else if (bid < 6444) {
    int b = bid - 6436;
    int nb = Ns[b];
    for (int t2 = tid; t2 < nb; t2 += 256)
      biasf[boff[b] + t2] = Bp[b][t2];
  } else if (bid == 6444) {
    int g = tid;
    if (g < 48) {
      float phi = dp[g * 3 + 0], theta = dp[g * 3 + 1], omega = dp[g * 3 + 2];
      float c = cosf(0.5f * theta), s = sinf(0.5f * theta);
      float a = 0.5f * (phi + omega), d = 0.5f * (phi - omega);
      float ca = cosf(a), sa = sinf(a), cd = cosf(d), sd = sinf(d);
      float* o = gw + g * 8;
      o[0] =  ca * c; o[1] = -sa * c;
      o[2] = -cd * s; o[3] = -sd * s;
      o[4] =  cd * s; o[5] = -sd * s;
      o[6] =  ca * c; o[7] =  sa * c;
    }
  } else if (do_x) {
    long i = ((long)(bid - 6445) * 256 + tid) * 8;
    if (i < 10485760L) {
      short8 v = ld8b(xf + i);
      *(short8*)((short*)xb + i) = v;
    }
  }
}

// ---------------- async MFMA GEMM: C = act(A @ Bt^T + bias)
// 2-deep counted-vmcnt pipeline: tiles t and t+1 in flight; per iteration
// wait vmcnt(LOADS) (tile t landed, t+1 still in flight), raw s_barrier
// (no drain), ds_read, lgkmcnt(0)+sched_barrier, barrier, restage buffer
// with tile t+2, then MFMA. Never vmcnt(0) until the final tile.
// ACT: 0=leaky, 1=tanh, 2=identity no-bias, 3=tanh + hi/lo/hi triple store
//      (A' builder: C is bf16 [M][768], n in [0,256)).
template <int BM, int BN, int BK, int WR, int WC, int ACT, typename TC>
__global__ __launch_bounds__(256) void gemm_async(const bf16* __restrict__ A,
                                                  const bf16* __restrict__ Bt,
                                                  const float* __restrict__ bias,
                                                  TC* __restrict__ C,
                                                  int M, int N, int K) {
  constexpr int CPR = BK / 8;
  constexpr int MASK = CPR - 1;
  constexpr int RPW = 64 / CPR;
  constexpr int RPP = 4 * RPW;
  constexpr int WMT = BM / WR;
  constexpr int WNT = BN / WC;
  constexpr int FI = WMT / 16;
  constexpr int FJ = WNT / 16;
  constexpr int KK = BK / 32;
  constexpr int LOADS = BM / RPP + BN / RPP;   // per-wave stages per tile
  static_assert(LOADS == 4 || LOADS == 6 || LOADS == 8, "vmcnt literal");
  __shared__ __align__(16) short As[2][BM * BK];
  __shared__ __align__(16) short Bs[2][BN * BK];
  const int tid = threadIdx.x;
  const int lane = tid & 63;
  const int wid = tid >> 6;
  const int wm = wid / WC, wn = wid % WC;
  const int bm = blockIdx.y * BM;
  const int bn = blockIdx.x * BN;

  const int st_r = lane / CPR;
  const int st_cs = (lane & MASK) ^ (st_r & MASK);

  const int frag_m = lane & 15;
  const int q = lane >> 4;

  auto stage = [&](int buf, int k0) {
#pragma unroll
    for (int p = 0; p < BM / RPP; ++p) {
      const bf16* g = A + (size_t)(bm + p * RPP + wid * RPW + st_r) * K + k0 + st_cs * 8;
      async_load16(g, &As[buf][(p * RPP + wid * RPW) * BK]);
    }
#pragma unroll
    for (int p = 0; p < BN / RPP; ++p) {
      const bf16* g = Bt + (size_t)(bn + p * RPP + wid * RPW + st_r) * K + k0 + st_cs * 8;
      async_load16(g, &Bs[buf][(p * RPP + wid * RPW) * BK]);
    }
  };

  f32x4 acc[FI][FJ] = {};

  const int nsteps = K / BK;
  stage(0, 0);
  if (nsteps > 1) stage(1, BK);

  for (int t = 0; t < nsteps - 1; ++t) {
    // tile t resident (own loads retired), tile t+1 stays in flight
    if constexpr (LOADS == 8) asm volatile("s_waitcnt vmcnt(8)" ::: "memory");
    else if constexpr (LOADS == 6) asm volatile("s_waitcnt vmcnt(6)" ::: "memory");
    else asm volatile("s_waitcnt vmcnt(4)" ::: "memory");
    __builtin_amdgcn_s_barrier();

    const short* Ac = As[t & 1];
    const short* Bc = Bs[t & 1];
    short8 af[FI][KK], bfr[FJ][KK];
#pragma unroll
    for (int i = 0; i < FI; ++i) {
      const int m = wm * WMT + i * 16 + frag_m;
#pragma unroll
      for (int kk = 0; kk < KK; ++kk) {
        const int slot = (kk * 4 + q) ^ (m & MASK);
        af[i][kk] = *(const short8*)&Ac[m * BK + slot * 8];
      }
    }
#pragma unroll
    for (int j = 0; j < FJ; ++j) {
      const int n = wn * WNT + j * 16 + frag_m;
#pragma unroll
      for (int kk = 0; kk < KK; ++kk) {
        const int slot = (kk * 4 + q) ^ (n & MASK);
        bfr[j][kk] = *(const short8*)&Bs[t & 1][n * BK + slot * 8];
      }
    }
    (void)Bc;
    // all my LDS reads retired -> safe for others to overwrite after barrier
    asm volatile("s_waitcnt lgkmcnt(0)" ::: "memory");
    __builtin_amdgcn_sched_barrier(0);
    __builtin_amdgcn_s_barrier();
    if (t + 2 < nsteps) stage(t & 1, (t + 2) * BK);

#pragma unroll
    for (int kk = 0; kk < KK; ++kk)
#pragma unroll
      for (int i = 0; i < FI; ++i)
#pragma unroll
        for (int j = 0; j < FJ; ++j)
          acc[i][j] = __builtin_amdgcn_mfma_f32_16x16x32_bf16(af[i][kk], bfr[j][kk], acc[i][j], 0, 0, 0);
  }

  // last tile: drain everything
  asm volatile("s_waitcnt vmcnt(0)" ::: "memory");
  __builtin_amdgcn_s_barrier();
  {
    const int t = nsteps - 1;
    const short* Ac = As[t & 1];
    const short* Bc = Bs[t & 1];
    short8 af[FI][KK], bfr[FJ][KK];
#pragma unroll
    for (int i = 0; i < FI; ++i) {
      const int m = wm * WMT + i * 16 + frag_m;
#pragma unroll
      for (int kk = 0; kk < KK; ++kk) {
        const int slot = (kk * 4 + q) ^ (m & MASK);
        af[i][kk] = *(const short8*)&Ac[m * BK + slot * 8];
      }
    }
#pragma unroll
    for (int j = 0; j < FJ; ++j) {
      const int n = wn * WNT + j * 16 + frag_m;
#pragma unroll
      for (int kk = 0; kk < KK; ++kk) {
        const int slot = (kk * 4 + q) ^ (n & MASK);
        bfr[j][kk] = *(const short8*)&Bc[n * BK + slot * 8];
      }
    }
#pragma unroll
    for (int kk = 0; kk < KK; ++kk)
#pragma unroll
      for (int i = 0; i < FI; ++i)
#pragma unroll
        for (int j = 0; j < FJ; ++j)
          acc[i][j] = __builtin_amdgcn_mfma_f32_16x16x32_bf16(af[i][kk], bfr[j][kk], acc[i][j], 0, 0, 0);
  }

  const int col_lane = lane & 15;
  const int row_quad = q << 2;
#pragma unroll
  for (int i = 0; i < FI; ++i) {
#pragma unroll
    for (int j = 0; j < FJ; ++j) {
      int n = bn + wn * WNT + j * 16 + col_lane;
      float bj = (ACT == 2) ? 0.f : bias[n];
#pragma unroll
      for (int r = 0; r < 4; ++r) {
        int m = bm + wm * WMT + i * 16 + row_quad + r;
        float v = acc[i][j][r] + bj;
        if (ACT == 0) {
          v = (v >= 0.f) ? v : 0.2f * v;
          stf(C, (size_t)m * N + n, v);
        } else if (ACT == 1) {
          stf(C, (size_t)m * N + n, fast_tanh(v));
        } else if (ACT == 2) {
          stf(C, (size_t)m * N + n, v);
        } else {
          float tv = fast_tanh(v);
          bf16 h = __float2bfloat16(tv);
          float lo = tv - __bfloat162float(h);
          size_t base = (size_t)m * 768 + n;
          ((bf16*)C)[base] = h;
          ((bf16*)C)[base + 256] = __float2bfloat16(lo);
          ((bf16*)C)[base + 512] = h;
        }
      }
    }
  }
}

// ---------------- fallback GEMM1 (f32 A and W) — used only if ws too small
__global__ __launch_bounds__(256) void gemm_cvt(const float* __restrict__ A,
                                                const float* __restrict__ W,
                                                const float* __restrict__ bias,
                                                bf16* __restrict__ C,
                                                int M, int N, int K) {
  __shared__ __align__(16) short As[128 * 40];
  __shared__ __align__(16) short Bs[128 * 40];
  const int tid = threadIdx.x;
  const int lane = tid & 63;
  const int wave = tid >> 6;
  const int wm = wave >> 1, wn = wave & 1;
  const int bm = blockIdx.y * 128;
  const int bn = blockIdx.x * 128;
  const int a_row0 = tid >> 2;
  const int a_kcol = (tid & 3) << 3;
  const int b_ncol = (tid & 31) << 2;
  const int b_krow = (tid >> 5) << 2;
  const int frag_m = lane & 15;
  const int frag_k = (lane >> 4) << 3;

  f32x4 acc[4][4] = {};

  for (int k0 = 0; k0 < K; k0 += 32) {
#pragma unroll
    for (int c = 0; c < 2; ++c) {
      const int row = c * 64 + a_row0;
      short8 v = ld8b(A + (size_t)(bm + row) * K + k0 + a_kcol);
      *(short8*)&As[row * 40 + a_kcol] = v;
    }
    short4v bv[4];
#pragma unroll
    for (int kk = 0; kk < 4; ++kk)
      bv[kk] = ld4b(W + (size_t)(k0 + b_krow + kk) * N + bn + b_ncol);
#pragma unroll
    for (int nn = 0; nn < 4; ++nn) {
      short4v w;
      w[0] = bv[0][nn]; w[1] = bv[1][nn]; w[2] = bv[2][nn]; w[3] = bv[3][nn];
      *(short4v*)&Bs[(b_ncol + nn) * 40 + b_krow] = w;
    }
    __syncthreads();
    short8 af[4], bfr[4];
#pragma unroll
    for (int i = 0; i < 4; ++i)
      af[i] = *(const short8*)&As[(wm * 64 + i * 16 + frag_m) * 40 + frag_k];
#pragma unroll
    for (int j = 0; j < 4; ++j)
      bfr[j] = *(const short8*)&Bs[(wn * 64 + j * 16 + frag_m) * 40 + frag_k];
#pragma unroll
    for (int i = 0; i < 4; ++i)
#pragma unroll
      for (int j = 0; j < 4; ++j)
        acc[i][j] = __builtin_amdgcn_mfma_f32_16x16x32_bf16(af[i], bfr[j], acc[i][j], 0, 0, 0);
    __syncthreads();
  }

  const int col_lane = lane & 15;
  const int row_quad = (lane >> 4) << 2;
#pragma unroll
  for (int i = 0; i < 4; ++i)
#pragma unroll
    for (int j = 0; j < 4; ++j) {
      int n = bn + wn * 64 + j * 16 + col_lane;
      float bj = bias[n];
#pragma unroll
      for (int r = 0; r < 4; ++r) {
        int m = bm + wm * 64 + i * 16 + row_quad + r;
        float v = acc[i][j][r] + bj;
        v = (v >= 0.f) ? v : 0.2f * v;
        stf(C, (size_t)m * N + n, v);
      }
    }
}

// ---------------- meas + fused d1 from PSI (have_xb fast path).
// PSI f32 [4096][512]: cols 0..255 = Re(p), 256..511 = Im(p), p = U @ enc
// (unnormalized). meas = quadratic_forms(p) / ||p||^2.
__global__ __launch_bounds__(256) void meas_d1(const float* __restrict__ PSI,
                                               const float* __restrict__ dw1,
                                               const float* __restrict__ db1,
                                               bf16* __restrict__ d1out) {
  const int tid = threadIdx.x;
  const int lane = tid & 63;
  const int b = blockIdx.x * 4 + (tid >> 6);

  const float* pp = PSI + (size_t)b * 512;
  float4 ar = *(const float4*)(pp + lane * 4);
  float4 ai = *(const float4*)(pp + 256 + lane * 4);
  float re[4] = {ar.x, ar.y, ar.z, ar.w};
  float im[4] = {ai.x, ai.y, ai.z, ai.w};

  float ss = 0.f;
#pragma unroll
  for (int j = 0; j < 4; ++j) ss += re[j] * re[j] + im[j] * im[j];
#pragma unroll
  for (int o = 32; o; o >>= 1) ss += __shfl_xor(ss, o, 64);
  const float inv = 1.0f / fmaxf(ss, 1e-24f);

  float mz[8], mx[8], my[8];
#pragma unroll
  for (int qq = 0; qq < 8; ++qq) {
    const int s = 1 << (7 - qq);
    float z = 0.f, x = 0.f, y = 0.f;
#pragma unroll
    for (int j = 0; j < 4; ++j) {
      float fr, fi;
      if (s >= 4) {
        fr = __shfl_xor(re[j], s >> 2, 64);
        fi = __shfl_xor(im[j], s >> 2, 64);
      } else {
        fr = re[j ^ s]; fi = im[j ^ s];
      }
      float prob = re[j] * re[j] + im[j] * im[j];
      int i = lane * 4 + j;
      float sg = (i & s) ? -1.f : 1.f;
      z += sg * prob;
      x += re[j] * fr + im[j] * fi;
      y += sg * (re[j] * fi - im[j] * fr);
    }
#pragma unroll
    for (int o = 32; o; o >>= 1) {
      z += __shfl_xor(z, o, 64);
      x += __shfl_xor(x, o, 64);
      y += __shfl_xor(y, o, 64);
    }
    mz[qq] = z * inv; mx[qq] = x * inv; my[qq] = y * inv;
  }

  // fused d1: leaky(meas @ dw1 + db1), dw1 f32 [24][128]
#pragma unroll
  for (int half = 0; half < 2; ++half) {
    const int n = lane + half * 64;
    float acc = db1[n];
#pragma unroll
    for (int qq = 0; qq < 8; ++qq) {
      acc += mz[qq] * dw1[qq * 128 + n];
      acc += mx[qq] * dw1[(8 + qq) * 128 + n];
      acc += my[qq] * dw1[(16 + qq) * 128 + n];
    }
    acc = (acc >= 0.f) ? acc : 0.2f * acc;
    d1out[(size_t)b * 128 + n] = __float2bfloat16(acc);
  }
}

// ---------------- legacy circuit + fused d1 (fallback when !have_xb)
__global__ __launch_bounds__(256) void circuit_wave(const float* __restrict__ enc,
                                                    const float* __restrict__ gw,
                                                    const float* __restrict__ dw1,
                                                    const float* __restrict__ db1,
                                                    bf16* __restrict__ d1out) {
  __shared__ float gsh[384];
  const int tid = threadIdx.x;
  for (int t = tid; t < 384; t += 256) gsh[t] = gw[t];
  __syncthreads();
  const int lane = tid & 63;
  const int b = blockIdx.x * 4 + (tid >> 6);

  float4 e = *(const float4*)(enc + (size_t)b * 256 + lane * 4);
  float re[4] = {e.x, e.y, e.z, e.w};
  float im[4] = {0.f, 0.f, 0.f, 0.f};
  float ss = e.x * e.x + e.y * e.y + e.z * e.z + e.w * e.w;
#pragma unroll
  for (int o = 32; o; o >>= 1) ss += __shfl_xor(ss, o, 64);
  float inv = 1.0f / fmaxf(sqrtf(ss), 1e-12f);
#pragma unroll
  for (int j = 0; j < 4; ++j) re[j] *= inv;

  run_circuit(re, im, gsh, lane);

  float mz[8], mx[8], my[8];
#pragma unroll
  for (int qq = 0; qq < 8; ++qq) {
    const int s = 1 << (7 - qq);
    float z = 0.f, x = 0.f, y = 0.f;
#pragma unroll
    for (int j = 0; j < 4; ++j) {
      float fr, fi;
      if (s >= 4) {
        fr = __shfl_xor(re[j], s >> 2, 64);
        fi = __shfl_xor(im[j], s >> 2, 64);
      } else {
        fr = re[j ^ s]; fi = im[j ^ s];
      }
      float prob = re[j] * re[j] + im[j] * im[j];
      int i = lane * 4 + j;
      float sg = (i & s) ? -1.f : 1.f;
      z += sg * prob;
      x += re[j] * fr + im[j] * fi;
      y += sg * (re[j] * fi - im[j] * fr);
    }
#pragma unroll
    for (int o = 32; o; o >>= 1) {
      z += __shfl_xor(z, o, 64);
      x += __shfl_xor(x, o, 64);
      y += __shfl_xor(y, o, 64);
    }
    mz[qq] = z; mx[qq] = x; my[qq] = y;
  }

#pragma unroll
  for (int half = 0; half < 2; ++half) {
    const int n = lane + half * 64;
    float acc = db1[n];
#pragma unroll
    for (int qq = 0; qq < 8; ++qq) {
      acc += mz[qq] * dw1[qq * 128 + n];
      acc += mx[qq] * dw1[(8 + qq) * 128 + n];
      acc += my[qq] * dw1[(16 + qq) * 128 + n];
    }
    acc = (acc >= 0.f) ? acc : 0.2f * acc;
    d1out[(size_t)b * 128 + n] = __float2bfloat16(acc);
  }
}

extern "C" void kernel_launch(void* const* d_in, const int* in_sizes, int n_in,
                              void* d_out, int out_size, void* d_ws, size_t ws_size,
                              hipStream_t stream) {
  (void)in_sizes; (void)n_in; (void)out_size;
  char* wsb = (char*)d_ws;
  float* gw    = (float*)(wsb + 256);
  float* biasf = (float*)(wsb + 4096);
  float* encf  = (float*)(wsb + 294912);       // fallback only
  bf16*  BtU   = (bf16*)(wsb + 294912);        // have_xb only (overlays encf)
  bf16*  P     = (bf16*)(wsb + 4489216);
  bf16*  Q     = (bf16*)(wsb + 12877824);
  bf16*  WT    = (bf16*)(wsb + 17072128);
  bf16*  Xb    = (bf16*)(wsb + 30253056);
  bf16*  Ap    = (bf16*)(wsb + 30253056);      // A' overlays Xb after GEMM1
  float* PSI   = (float*)(wsb + 36544512);
  const bool have_xb = ws_size >= 51224576;

  bf16* ew1t = WT + 0;
  bf16* ew2t = WT + 2621440;
  bf16* ew3t = WT + 3145728;
  bf16* dw2t = WT + 3280896;
  bf16* dw3t = WT + 3313664;
  bf16* dw4t = WT + 3444736;
  bf16* dw5t = WT + 3969024;
  float* beb1 = biasf + 0;
  float* beb2 = biasf + 1024;
  float* beb3 = biasf + 1536;
  float* bdb2 = biasf + 1920;
  float* bdb3 = biasf + 2176;
  float* bdb4 = biasf + 2688;
  float* bdb5 = biasf + 3712;

  prep_all<<<11629, 256, 0, stream>>>(
      (const float*)d_in[1], (const float*)d_in[3], (const float*)d_in[5],
      (const float*)d_in[8], (const float*)d_in[10], (const float*)d_in[12],
      (const float*)d_in[14], (const float*)d_in[16],
      (const float*)d_in[2], (const float*)d_in[4], (const float*)d_in[6],
      (const float*)d_in[9], (const float*)d_in[11], (const float*)d_in[13],
      (const float*)d_in[15], (const float*)d_in[17],
      (const float*)d_in[7], (const float*)d_in[0],
      WT, biasf, gw, Xb, BtU, have_xb ? 1 : 0);

  // ---- GEMM1: h1 = leaky(x @ ew1 + eb1)   [4096x1024, K=2560]
  if (have_xb) {
    gemm_async<128, 64, 64, 4, 1, 0, bf16><<<dim3(16, 32), 256, 0, stream>>>(
        Xb, ew1t, beb1, P, 4096, 1024, 2560);
  } else {
    gemm_cvt<<<dim3(8, 32), 256, 0, stream>>>(
        (const float*)d_in[0], (const float*)d_in[1], beb1, P, 4096, 1024, 2560);
  }

  // ---- GEMM2: h2 = leaky(h1 @ ew2 + eb2)  [4096x512, K=1024]
  gemm_async<64, 64, 64, 2, 2, 0, bf16><<<dim3(8, 64), 256, 0, stream>>>(
      P, ew2t, beb2, Q, 4096, 512, 1024);

  if (have_xb) {
    // ---- GEMM3: A' = hi/lo/hi(tanh(h2 @ ew3 + eb3))  [4096x768 bf16]
    gemm_async<64, 64, 64, 2, 2, 3, bf16><<<dim3(4, 64), 256, 0, stream>>>(
        Q, ew3t, beb3, Ap, 4096, 256, 512);
    // ---- PSI = A' @ BtU^T  [4096x512 f32, K=768] (compensated bf16 GEMM)
    gemm_async<64, 64, 64, 2, 2, 2, float><<<dim3(8, 64), 256, 0, stream>>>(
        Ap, BtU, beb3 /*unused*/, PSI, 4096, 512, 768);
    // ---- measurements + fused d1 -> Q bf16 [4096][128]
    meas_d1<<<1024, 256, 0, stream>>>(PSI, (const float*)d_in[8],
                                      (const float*)d_in[9], Q);
  } else {
    // ---- GEMM3: enc = tanh(h2 @ ew3 + eb3)  [4096x256 f32]
    gemm_async<64, 64, 64, 2, 2, 1, float><<<dim3(4, 64), 256, 0, stream>>>(
        Q, ew3t, beb3, encf, 4096, 256, 512);
    circuit_wave<<<1024, 256, 0, stream>>>(encf, gw, (const float*)d_in[8],
                                           (const float*)d_in[9], Q);
  }

  // ---- decoder
  gemm_async<64, 64, 64, 2, 2, 0, bf16><<<dim3(4, 64), 256, 0, stream>>>(
      Q, dw2t, bdb2, P, 4096, 256, 128);
  gemm_async<64, 64, 64, 2, 2, 0, bf16><<<dim3(8, 64), 256, 0, stream>>>(
      P, dw3t, bdb3, Q, 4096, 512, 256);
  gemm_async<128, 64, 64, 4, 1, 0, bf16><<<dim3(16, 32), 256, 0, stream>>>(
      Q, dw4t, bdb4, P, 4096, 1024, 512);
  // ---- d5: out = tanh(d4 @ dw5 + db5)  [4096x2560, K=1024] -> f32
  gemm_async<128, 128, 64, 2, 2, 1, float><<<dim3(20, 32), 256, 0, stream>>>(
      P, dw5t, bdb5, (float*)d_out, 4096, 2560, 1024);
}